// Round 7
// baseline (13834.335 us; speedup 1.0000x reference)
//
#include <hip/hip_runtime.h>
#include <hip/hip_bf16.h>

#define T_STEPS 512
#define BATCH   64
#define INW     512
#define HID     1024
#define BH      (BATCH * HID)   // 65536

typedef __bf16 bf16x8 __attribute__((ext_vector_type(8)));
typedef float  f32x4  __attribute__((ext_vector_type(4)));
typedef float  f4     __attribute__((ext_vector_type(4)));

__device__ __forceinline__ bf16x8 load8_cvt(const float* p) {
  const f4* q = (const f4*)p;
  f4 a = q[0], b = q[1];
  bf16x8 r;
  r[0]=(__bf16)a[0]; r[1]=(__bf16)a[1]; r[2]=(__bf16)a[2]; r[3]=(__bf16)a[3];
  r[4]=(__bf16)b[0]; r[5]=(__bf16)b[1]; r[6]=(__bf16)b[2]; r[7]=(__bf16)b[3];
  return r;
}

// ---- prep: rearrange [w_ih | w_hh] into per-jtile contiguous bf16 rows ----
// wre[jt][lr][k], lr = g*16 + jl -> global gate row G = g*1024 + jt*16 + jl,
// k<512 from w_ih, k>=512 from w_hh.
__global__ void gru_prep_w(const float* __restrict__ w_ih,
                           const float* __restrict__ w_hh,
                           __bf16* __restrict__ wre) {
  const int row = blockIdx.x;            // 0..3071 = jt*48 + lr
  const int jt = row / 48, lr = row % 48;
  const int g = lr >> 4, jl = lr & 15;
  const int G = g * HID + jt * 16 + jl;
  __bf16* dst = wre + (size_t)row * 1536;
  for (int k = threadIdx.x; k < 1536; k += 256)
    dst[k] = (__bf16)((k < INW) ? w_ih[(size_t)G * INW + k]
                                : w_hh[(size_t)G * HID + (k - INW)]);
}

__global__ void gru_prep_b(const float* __restrict__ b_ih,
                           const float* __restrict__ b_hh,
                           float* __restrict__ bias4) {
  const int j = blockIdx.x * 256 + threadIdx.x;
  if (j < HID) {
    bias4[4*j+0] = b_ih[j]        + b_hh[j];          // r
    bias4[4*j+1] = b_ih[HID+j]    + b_hh[HID+j];      // z
    bias4[4*j+2] = b_ih[2*HID+j];                     // n, x-side
    bias4[4*j+3] = b_hh[2*HID+j];                     // n, h-side
  }
}

// ---- one GRU timestep. Grid 64 WGs (jt = 16 h-cols), 4 waves = batch tiles.
// No cross-WG communication: kernel boundary provides coherence for hb16/hf32.
// acc C/D layout (m89/AMD blog): col(j) = lane&15, row(batch) = (lane>>4)*4+i,
// so r,z,nx,nh for one (b,j) live in the SAME lane & reg -> no LDS reduction.
__global__ void __launch_bounds__(256, 1)
gru_step(const float* __restrict__ x, const __bf16* __restrict__ wre,
         const float* __restrict__ bias4, float* __restrict__ hf32,
         const __bf16* __restrict__ hb_r, __bf16* __restrict__ hb_w,
         float* __restrict__ out, int t)
{
  const int jt   = blockIdx.x;       // 0..63
  const int tid  = threadIdx.x;
  const int lane = tid & 63;
  const int wv   = tid >> 6;         // wave = batch tile (16 rows)
  const int jl   = lane & 15;        // A-row within tile / C-col within tile
  const int kq   = lane >> 4;        // k-quarter (8 elems each)

  f32x4 accr = {0,0,0,0}, accz = {0,0,0,0};
  f32x4 accnx = {0,0,0,0}, accnh = {0,0,0,0};

  const __bf16* wbase = wre + (size_t)jt * 48 * 1536;
  const int nchunk = (t == 0) ? 2 : 6;   // chunks 0,1 = x-part; 2..5 = h-part

  for (int c = 0; c < nchunk; ++c) {
    const int kc = c * 256;

    // A-frags: rows = batches wv*16 + jl, k = kc + s*32 + kq*8 (+0..7)
    bf16x8 af[8];
    if (c < 2) {
      const float* xb = x + ((size_t)t * BATCH + wv * 16 + jl) * INW + kc + kq * 8;
#pragma unroll
      for (int s = 0; s < 8; ++s) af[s] = load8_cvt(xb + s * 32);
    } else {
      const __bf16* hbp = hb_r + (size_t)(wv * 16 + jl) * HID + (kc - INW) + kq * 8;
#pragma unroll
      for (int s = 0; s < 8; ++s) af[s] = *(const bf16x8*)(hbp + s * 32);
    }

    // B-frags straight from L2-resident wre (full 64B-line use), 3 gates
    const __bf16* w0 = wbase + (size_t)(jl)      * 1536 + kc + kq * 8; // r
    const __bf16* w1 = wbase + (size_t)(16 + jl) * 1536 + kc + kq * 8; // z
    const __bf16* w2 = wbase + (size_t)(32 + jl) * 1536 + kc + kq * 8; // n
#pragma unroll
    for (int s = 0; s < 8; ++s) {
      const bf16x8 b0 = *(const bf16x8*)(w0 + s * 32);
      const bf16x8 b1 = *(const bf16x8*)(w1 + s * 32);
      const bf16x8 b2 = *(const bf16x8*)(w2 + s * 32);
      accr = __builtin_amdgcn_mfma_f32_16x16x32_bf16(af[s], b0, accr, 0, 0, 0);
      accz = __builtin_amdgcn_mfma_f32_16x16x32_bf16(af[s], b1, accz, 0, 0, 0);
      if (c < 2)
        accnx = __builtin_amdgcn_mfma_f32_16x16x32_bf16(af[s], b2, accnx, 0, 0, 0);
      else
        accnh = __builtin_amdgcn_mfma_f32_16x16x32_bf16(af[s], b2, accnh, 0, 0, 0);
    }
  }

  // ---- epilogue: this lane owns col j for 4 batches (rows kq*4+i) ----
  const int j = jt * 16 + jl;
  const f4 b4 = *(const f4*)(bias4 + 4 * j);
#pragma unroll
  for (int i = 0; i < 4; ++i) {
    const int b = wv * 16 + kq * 4 + i;
    const float hp = (t == 0) ? 0.0f : hf32[b * HID + j];
    const float r  = 1.0f / (1.0f + __expf(-(accr[i] + b4[0])));
    const float z  = 1.0f / (1.0f + __expf(-(accz[i] + b4[1])));
    const float nv = accnx[i] + b4[2] + r * (accnh[i] + b4[3]);
    const float n  = 1.0f - 2.0f / (1.0f + __expf(2.0f * nv));   // tanh
    const float hn = (1.0f - z) * n + z * hp;

    out[(size_t)t * BH + b * HID + j] = hn;
    hf32[b * HID + j] = hn;
    hb_w[b * HID + j] = (__bf16)hn;
    if (t == T_STEPS - 1)
      out[(size_t)T_STEPS * BH + b * HID + j] = hn;
  }
}

extern "C" void kernel_launch(void* const* d_in, const int* in_sizes, int n_in,
                              void* d_out, int out_size, void* d_ws, size_t ws_size,
                              hipStream_t stream) {
  (void)in_sizes; (void)n_in; (void)out_size; (void)ws_size;
  const float* x    = (const float*)d_in[0];
  const float* w_ih = (const float*)d_in[1];
  const float* w_hh = (const float*)d_in[2];
  const float* b_ih = (const float*)d_in[3];
  const float* b_hh = (const float*)d_in[4];
  float* out        = (float*)d_out;

  // ws layout (≈9.6 MB total)
  char* ws = (char*)d_ws;
  __bf16* wre   = (__bf16*)(ws);                         // 64*48*1536*2 = 9,437,184
  float*  bias4 = (float*)(ws + 9437184);                // 16,384
  float*  hf32  = (float*)(ws + 9453568);                // 262,144
  __bf16* hb0   = (__bf16*)(ws + 9715712);               // 131,072
  __bf16* hb1   = (__bf16*)(ws + 9846784);               // 131,072

  gru_prep_w<<<3072, 256, 0, stream>>>(w_ih, w_hh, wre);
  gru_prep_b<<<4, 256, 0, stream>>>(b_ih, b_hh, bias4);

  for (int t = 0; t < T_STEPS; ++t) {
    const __bf16* hb_r = (t & 1) ? hb0 : hb1;   // written by step t-1
    __bf16*       hb_w = (t & 1) ? hb1 : hb0;
    gru_step<<<64, 256, 0, stream>>>(x, wre, bias4, hf32, hb_r, hb_w, out, t);
  }
}